// Round 3
// baseline (5592.633 us; speedup 1.0000x reference)
//
#include <hip/hip_runtime.h>
#include <cmath>

// Problem constants
#define BB 64
#define RR 4608
#define CC 32
#define INN 8
#define OUTT 16

constexpr int RPH    = 4;               // r rows per phase
constexpr int NPH    = 6;               // phases per block
constexpr int RCB    = RPH * NPH;       // 24 r per block
constexpr int NCHUNK = RR / RCB;        // 192
constexpr int CT     = 4;               // c per block (one wave each)

typedef __attribute__((address_space(3))) void  lds_void;
typedef __attribute__((address_space(1))) const void  gbl_void;

// Flash-style routing pass. lane=b, wave=c. Both x and W double-buffered in LDS
// via global_load_lds (linear dest, per-lane source), counted vmcnt pipeline.
__global__ __launch_bounds__(256, 4)
void caps_pass(const float* __restrict__ x, const float* __restrict__ W,
               const float* __restrict__ V, float* __restrict__ pz,
               float* __restrict__ ps)
{
    __shared__ float xls[2][RPH * BB * INN];        // 2 x 8 KB  [r][b][i]
    __shared__ float wls[2][RPH * CT * INN * OUTT]; // 2 x 8 KB  [r][c][i*16+o]

    const int tid  = threadIdx.x;
    const int lane = tid & 63;                       // = b
    const int wv   = __builtin_amdgcn_readfirstlane(tid >> 6); // 0..3
    const int ch   = blockIdx.x;                     // 0..191
    const int r0   = ch * RCB;
    const int c0   = blockIdx.y * CT;
    const int c    = c0 + wv;

    // Issue one phase's staging: wave wv stages global row (r0 + p*RPH + wv)
    // for both x (all 64 b, 8 i) and W (4 c, 128 floats). 4 calls/wave/phase.
    auto issue_phase = [&](int p, int buf) {
        const int rw = r0 + p * RPH + wv;
#pragma unroll
        for (int k = 0; k < 2; ++k) {
            const int within = k * 64 + lane;        // 0..127 (float4 slot in row)
            const int b      = within >> 1;
            const int half   = within & 1;
            const float* gx = x + ((size_t)b * RR + rw) * INN + half * 4;
            float* lx = &xls[buf][(wv * 128 + k * 64) * 4];
            __builtin_amdgcn_global_load_lds(
                (gbl_void*)gx,
                (lds_void*)(__attribute__((address_space(3))) float*)lx, 16, 0, 0);
        }
#pragma unroll
        for (int k = 0; k < 2; ++k) {
            const int within = k * 64 + lane;
            const int cl     = within >> 5;          // 0..3
            const int f4     = within & 31;
            const float* gw = W + ((size_t)rw * CC + c0 + cl) * (INN * OUTT) + f4 * 4;
            float* lw = &wls[buf][(wv * 128 + k * 64) * 4];
            __builtin_amdgcn_global_load_lds(
                (gbl_void*)gw,
                (lds_void*)(__attribute__((address_space(3))) float*)lw, 16, 0, 0);
        }
    };

    // Cumulative V for (b=lane, c) -- loaded FIRST so phase prefetches are newer
    // in the vmcnt queue.
    float Vr[OUTT];
    {
        const float* vp = V + ((size_t)c * BB + lane) * OUTT;
        const float4 v0 = *reinterpret_cast<const float4*>(vp);
        const float4 v1 = *reinterpret_cast<const float4*>(vp + 4);
        const float4 v2 = *reinterpret_cast<const float4*>(vp + 8);
        const float4 v3 = *reinterpret_cast<const float4*>(vp + 12);
        Vr[0]=v0.x; Vr[1]=v0.y; Vr[2]=v0.z; Vr[3]=v0.w;
        Vr[4]=v1.x; Vr[5]=v1.y; Vr[6]=v1.z; Vr[7]=v1.w;
        Vr[8]=v2.x; Vr[9]=v2.y; Vr[10]=v2.z; Vr[11]=v2.w;
        Vr[12]=v3.x; Vr[13]=v3.y; Vr[14]=v3.z; Vr[15]=v3.w;
    }

    issue_phase(0, 0);
    issue_phase(1, 1);

    float z = 0.f;
    float sacc[OUTT];
#pragma unroll
    for (int o = 0; o < OUTT; ++o) sacc[o] = 0.f;

    for (int p = 0; p < NPH; ++p) {
        const int cur = p & 1;

        // Counted wait: keep next phase's 4 loads in flight (T4). Only the
        // last phase drains to 0.
        if (p < NPH - 1) asm volatile("s_waitcnt vmcnt(4)" ::: "memory");
        else             asm volatile("s_waitcnt vmcnt(0)" ::: "memory");
        __builtin_amdgcn_s_barrier();
        asm volatile("" ::: "memory");

#pragma unroll
        for (int rl = 0; rl < RPH; ++rl) {
            const float4 xA = *reinterpret_cast<const float4*>(
                &xls[cur][rl * 512 + lane * 8]);
            const float4 xB = *reinterpret_cast<const float4*>(
                &xls[cur][rl * 512 + lane * 8 + 4]);
            const float xv[INN] = { xA.x, xA.y, xA.z, xA.w,
                                    xB.x, xB.y, xB.z, xB.w };

            const float4* W4 = reinterpret_cast<const float4*>(
                &wls[cur][rl * 512 + wv * 128]);    // wave-uniform -> broadcast

            float uh[OUTT];
#pragma unroll
            for (int o = 0; o < OUTT; ++o) uh[o] = 0.f;
#pragma unroll
            for (int i = 0; i < INN; ++i) {
                const float xi = xv[i];
                const float4 wa = W4[i * 4 + 0];
                const float4 wb = W4[i * 4 + 1];
                const float4 wc = W4[i * 4 + 2];
                const float4 wd = W4[i * 4 + 3];
                uh[0]  = fmaf(xi, wa.x, uh[0]);  uh[1]  = fmaf(xi, wa.y, uh[1]);
                uh[2]  = fmaf(xi, wa.z, uh[2]);  uh[3]  = fmaf(xi, wa.w, uh[3]);
                uh[4]  = fmaf(xi, wb.x, uh[4]);  uh[5]  = fmaf(xi, wb.y, uh[5]);
                uh[6]  = fmaf(xi, wb.z, uh[6]);  uh[7]  = fmaf(xi, wb.w, uh[7]);
                uh[8]  = fmaf(xi, wc.x, uh[8]);  uh[9]  = fmaf(xi, wc.y, uh[9]);
                uh[10] = fmaf(xi, wc.z, uh[10]); uh[11] = fmaf(xi, wc.w, uh[11]);
                uh[12] = fmaf(xi, wd.x, uh[12]); uh[13] = fmaf(xi, wd.y, uh[13]);
                uh[14] = fmaf(xi, wd.z, uh[14]); uh[15] = fmaf(xi, wd.w, uh[15]);
            }

            float logit = 0.f;
#pragma unroll
            for (int o = 0; o < OUTT; ++o) logit = fmaf(uh[o], Vr[o], logit);

            const float pexp = __expf(logit);   // V=0 on iter0 -> uniform routing
            z += pexp;
#pragma unroll
            for (int o = 0; o < OUTT; ++o) sacc[o] = fmaf(pexp, uh[o], sacc[o]);
        }

        // All waves done reading buf[cur] before its overwrite.
        asm volatile("" ::: "memory");
        __builtin_amdgcn_s_barrier();
        asm volatile("" ::: "memory");
        if (p + 2 < NPH) issue_phase(p + 2, cur);
    }

    // write partials
    const size_t base = ((size_t)ch * CC + c) * BB + lane;
    pz[base] = z;
    float* psp = ps + base * OUTT;
#pragma unroll
    for (int q = 0; q < OUTT / 4; ++q) {
        float4 v4 = make_float4(sacc[4 * q], sacc[4 * q + 1],
                                sacc[4 * q + 2], sacc[4 * q + 3]);
        *reinterpret_cast<float4*>(psp + 4 * q) = v4;
    }
}

// Combine partials over r-chunks, squash, accumulate V or emit output.
template <int LAST>
__global__ __launch_bounds__(256)
void caps_combine(const float* __restrict__ pz, const float* __restrict__ ps,
                  float* __restrict__ V, float* __restrict__ out)
{
    const int tid = blockIdx.x * 256 + threadIdx.x;  // 0..32767
    const int o  = tid & 15;
    const int bc = tid >> 4;        // 0..2047
    const int b  = bc & 63;
    const int c  = bc >> 6;

    float Z = 0.f, sv = 0.f;
#pragma unroll 4
    for (int chk = 0; chk < NCHUNK; ++chk) {
        const size_t base = ((size_t)chk * CC + c) * BB + b;
        Z  += pz[base];
        sv += ps[base * OUTT + o];
    }
    float st = sv / Z;              // s[b,c,o]

    float sq = st * st;
#pragma unroll
    for (int m = 1; m < 16; m <<= 1) sq += __shfl_xor(sq, m);
    float scale = (sq / (1.0f + sq)) / sqrtf(sq + 1e-8f);
    float v = st * scale;

    if (LAST) {
        out[((size_t)b * CC + c) * OUTT + o] = v;      // (B,C,OUT)
    } else {
        V[((size_t)c * BB + b) * OUTT + o] += v;       // cumulative logit vector
    }
}

extern "C" void kernel_launch(void* const* d_in, const int* in_sizes, int n_in,
                              void* d_out, int out_size, void* d_ws, size_t ws_size,
                              hipStream_t stream)
{
    const float* x = (const float*)d_in[0];   // (B,R,IN)
    const float* W = (const float*)d_in[1];   // (R,C,IN,OUT)
    float* out = (float*)d_out;               // (B,C,OUT)

    float* wsf = (float*)d_ws;
    float* V  = wsf;                                    // 32768 floats
    float* pz = wsf + (size_t)BB * CC * OUTT;           // NCHUNK*C*B
    float* ps = pz + (size_t)NCHUNK * CC * BB;          // NCHUNK*C*B*16

    hipMemsetAsync(V, 0, (size_t)BB * CC * OUTT * sizeof(float), stream);

    dim3 grid(NCHUNK, CC / CT);
    for (int it = 0; it < 3; ++it) {
        caps_pass<<<grid, 256, 0, stream>>>(x, W, V, pz, ps);
        if (it < 2)
            caps_combine<0><<<128, 256, 0, stream>>>(pz, ps, V, out);
        else
            caps_combine<1><<<128, 256, 0, stream>>>(pz, ps, V, out);
    }
}

// Round 4
// 391.146 us; speedup vs baseline: 14.2981x; 14.2981x over previous
//
#include <hip/hip_runtime.h>
#include <cmath>

// Problem constants
#define BB 64
#define RR 4608
#define CC 32
#define INN 8
#define OUTT 16

constexpr int RSUB   = 8;               // r rows per W-staging sub-chunk
constexpr int NSUB   = 3;               // sub-chunks per block
constexpr int RCB    = RSUB * NSUB;     // 24 r per block
constexpr int NCHUNK = RR / RCB;        // 192
constexpr int CT     = 4;               // c per block (one wave each)

// Flash-style routing pass. lane = b (64), wave = c (4 per block).
// W staged in LDS per 8-r sub-chunk (cooperative, coalesced), consumed as
// wave-uniform ds_read_b128 broadcasts. x read per-lane from global (L2),
// prefetched one r-pair ahead in registers. No reg arrays live across
// barriers except one float4 pair (8 VGPR).
__global__ __launch_bounds__(256, 4)
void caps_pass(const float* __restrict__ x, const float* __restrict__ W,
               const float* __restrict__ V, float* __restrict__ pz,
               float* __restrict__ ps)
{
    __shared__ float wl[RSUB][CT * INN * OUTT];   // [8][512] floats = 16 KB

    const int tid  = threadIdx.x;
    const int lane = tid & 63;                    // = b
    const int wv   = __builtin_amdgcn_readfirstlane(tid >> 6); // 0..3
    const int ch   = blockIdx.x;                  // 0..191
    const int r0   = ch * RCB;
    const int c0   = blockIdx.y * CT;
    const int c    = c0 + wv;

    // cumulative V for (b=lane, c)
    float Vr[OUTT];
    {
        const float* vp = V + ((size_t)c * BB + lane) * OUTT;
#pragma unroll
        for (int q = 0; q < 4; ++q) {
            float4 v4 = *reinterpret_cast<const float4*>(vp + 4 * q);
            Vr[4*q+0] = v4.x; Vr[4*q+1] = v4.y; Vr[4*q+2] = v4.z; Vr[4*q+3] = v4.w;
        }
    }

    float z = 0.f;
    float sacc[OUTT];
#pragma unroll
    for (int o = 0; o < OUTT; ++o) sacc[o] = 0.f;

    const float* xrow_base = x + (size_t)lane * RR * INN;

    for (int s = 0; s < NSUB; ++s) {
        const int rs = r0 + s * RSUB;
        const float* xrow = xrow_base + (size_t)rs * INN;   // lane's 64 floats

        // Issue first x pair early: latency hides under W stage + barrier.
        float4 xa = *reinterpret_cast<const float4*>(xrow);
        float4 xb = *reinterpret_cast<const float4*>(xrow + 4);

        // ---- stage W sub-chunk: 8 r x 4 c x 128 floats = 16 KB, coalesced.
        // Immediate load->store pairs; nothing held across the barrier.
#pragma unroll
        for (int k = 0; k < 4; ++k) {
            const int j   = k * 256 + tid;       // 0..1023 float4 slots
            const int rq  = j >> 7;              // 0..7
            const int pos = j & 127;             // float4 within 2KB row-slice
            float4 t = *reinterpret_cast<const float4*>(
                W + ((size_t)(rs + rq) * CC + c0) * (INN * OUTT) + pos * 4);
            *reinterpret_cast<float4*>(&wl[rq][pos * 4]) = t;
        }
        __syncthreads();

#pragma unroll
        for (int rl = 0; rl < RSUB; ++rl) {
            // prefetch next r-pair (~340 cy of compute covers L2 latency)
            float4 xc, xd;
            if (rl + 1 < RSUB) {
                xc = *reinterpret_cast<const float4*>(xrow + (rl + 1) * 8);
                xd = *reinterpret_cast<const float4*>(xrow + (rl + 1) * 8 + 4);
            }

            const float xv[INN] = { xa.x, xa.y, xa.z, xa.w,
                                    xb.x, xb.y, xb.z, xb.w };
            const float4* W4 = reinterpret_cast<const float4*>(
                &wl[rl][wv * 128]);              // wave-uniform -> broadcast

            float uh[OUTT];
#pragma unroll
            for (int o = 0; o < OUTT; ++o) uh[o] = 0.f;
#pragma unroll
            for (int i = 0; i < INN; ++i) {
                const float xi = xv[i];
                const float4 wa = W4[i * 4 + 0];
                const float4 wb = W4[i * 4 + 1];
                const float4 wc = W4[i * 4 + 2];
                const float4 wd = W4[i * 4 + 3];
                uh[0]  = fmaf(xi, wa.x, uh[0]);  uh[1]  = fmaf(xi, wa.y, uh[1]);
                uh[2]  = fmaf(xi, wa.z, uh[2]);  uh[3]  = fmaf(xi, wa.w, uh[3]);
                uh[4]  = fmaf(xi, wb.x, uh[4]);  uh[5]  = fmaf(xi, wb.y, uh[5]);
                uh[6]  = fmaf(xi, wb.z, uh[6]);  uh[7]  = fmaf(xi, wb.w, uh[7]);
                uh[8]  = fmaf(xi, wc.x, uh[8]);  uh[9]  = fmaf(xi, wc.y, uh[9]);
                uh[10] = fmaf(xi, wc.z, uh[10]); uh[11] = fmaf(xi, wc.w, uh[11]);
                uh[12] = fmaf(xi, wd.x, uh[12]); uh[13] = fmaf(xi, wd.y, uh[13]);
                uh[14] = fmaf(xi, wd.z, uh[14]); uh[15] = fmaf(xi, wd.w, uh[15]);
            }

            // logit = uh . Vr, 4-way tree for ILP
            float l0 = 0.f, l1 = 0.f, l2 = 0.f, l3 = 0.f;
#pragma unroll
            for (int q = 0; q < 4; ++q) {
                l0 = fmaf(uh[q],      Vr[q],      l0);
                l1 = fmaf(uh[4 + q],  Vr[4 + q],  l1);
                l2 = fmaf(uh[8 + q],  Vr[8 + q],  l2);
                l3 = fmaf(uh[12 + q], Vr[12 + q], l3);
            }
            const float logit = (l0 + l1) + (l2 + l3);

            const float pexp = __expf(logit);   // V=0 on iter0 -> uniform
            z += pexp;
#pragma unroll
            for (int o = 0; o < OUTT; ++o) sacc[o] = fmaf(pexp, uh[o], sacc[o]);

            xa = xc; xb = xd;                    // rotate prefetch
        }
        __syncthreads();                         // wl reused next sub-chunk
    }

    // write partials
    const size_t base = ((size_t)ch * CC + c) * BB + lane;
    pz[base] = z;
    float* psp = ps + base * OUTT;
#pragma unroll
    for (int q = 0; q < OUTT / 4; ++q) {
        float4 v4 = make_float4(sacc[4 * q], sacc[4 * q + 1],
                                sacc[4 * q + 2], sacc[4 * q + 3]);
        *reinterpret_cast<float4*>(psp + 4 * q) = v4;
    }
}

// Combine partials over r-chunks, squash, accumulate V or emit output.
template <int LAST>
__global__ __launch_bounds__(256)
void caps_combine(const float* __restrict__ pz, const float* __restrict__ ps,
                  float* __restrict__ V, float* __restrict__ out)
{
    const int tid = blockIdx.x * 256 + threadIdx.x;  // 0..32767
    const int o  = tid & 15;
    const int bc = tid >> 4;        // 0..2047
    const int b  = bc & 63;
    const int c  = bc >> 6;

    float Z = 0.f, sv = 0.f;
#pragma unroll 8
    for (int chk = 0; chk < NCHUNK; ++chk) {
        const size_t base = ((size_t)chk * CC + c) * BB + b;
        Z  += pz[base];
        sv += ps[base * OUTT + o];
    }
    float st = sv / Z;              // s[b,c,o]

    float sq = st * st;
#pragma unroll
    for (int m = 1; m < 16; m <<= 1) sq += __shfl_xor(sq, m);
    float scale = (sq / (1.0f + sq)) / sqrtf(sq + 1e-8f);
    float v = st * scale;

    if (LAST) {
        out[((size_t)b * CC + c) * OUTT + o] = v;      // (B,C,OUT)
    } else {
        V[((size_t)c * BB + b) * OUTT + o] += v;       // cumulative logits
    }
}

extern "C" void kernel_launch(void* const* d_in, const int* in_sizes, int n_in,
                              void* d_out, int out_size, void* d_ws, size_t ws_size,
                              hipStream_t stream)
{
    const float* x = (const float*)d_in[0];   // (B,R,IN)
    const float* W = (const float*)d_in[1];   // (R,C,IN,OUT)
    float* out = (float*)d_out;               // (B,C,OUT)

    float* wsf = (float*)d_ws;
    float* V  = wsf;                                    // 32768 floats
    float* pz = wsf + (size_t)BB * CC * OUTT;           // NCHUNK*C*B
    float* ps = pz + (size_t)NCHUNK * CC * BB;          // NCHUNK*C*B*16

    hipMemsetAsync(V, 0, (size_t)BB * CC * OUTT * sizeof(float), stream);

    dim3 grid(NCHUNK, CC / CT);
    for (int it = 0; it < 3; ++it) {
        caps_pass<<<grid, 256, 0, stream>>>(x, W, V, pz, ps);
        if (it < 2)
            caps_combine<0><<<128, 256, 0, stream>>>(pz, ps, V, out);
        else
            caps_combine<1><<<128, 256, 0, stream>>>(pz, ps, V, out);
    }
}